// Round 1
// baseline (371.942 us; speedup 1.0000x reference)
//
#include <hip/hip_runtime.h>

// Problem constants (match reference)
#define C_   64
#define H_   256
#define W_   256
#define L0_  1024
#define L1_  1024
#define ITILE 4   // output rows (i) per block

// Bicubic convolution taps/weights, matches PyTorch grid_sample
// (bicubic, padding_mode='border', align_corners=True), A = -0.75.
__device__ __forceinline__ void cubic_prep(float g, int size, int idx[4], float w[4]) {
    const float A = -0.75f;
    float x  = (g + 1.0f) * 0.5f * (float)(size - 1);   // align_corners=True unnormalize
    float x0 = floorf(x);
    float t  = x - x0;
    int   ix = (int)x0;
    float t2 = t * t, t3 = t2 * t;
    w[0] = A * (t3 - 2.0f * t2 + t);
    w[1] = (A + 2.0f) * t3 - (A + 3.0f) * t2 + 1.0f;
    float s = 1.0f - t, s2 = s * s;
    w[2] = (A + 2.0f) * s2 * s - (A + 3.0f) * s2 + 1.0f;
    float u = 2.0f - t, u2 = u * u;
    w[3] = A * u2 * u - 5.0f * A * u2 + 8.0f * A * u - 4.0f * A;
    // border clamp
    idx[0] = min(max(ix - 1, 0), size - 1);
    idx[1] = min(max(ix,     0), size - 1);
    idx[2] = min(max(ix + 1, 0), size - 1);
    idx[3] = min(max(ix + 2, 0), size - 1);
}

// Block = (c, 4 consecutive output rows i). Separable bicubic:
//  Phase 1: x-interpolate each of the 256 image rows at the 4 i's -> hx in LDS.
//  Phase 2: y-interpolate for all 1024 j's, float4 coalesced stores.
__global__ __launch_bounds__(256) void bicubic_kernel(const float* __restrict__ v,
                                                      const float* __restrict__ g0,
                                                      const float* __restrict__ g1,
                                                      float* __restrict__ out) {
    __shared__ float hx[ITILE][H_];   // 4 KB

    const int c  = blockIdx.y;
    const int i0 = blockIdx.x * ITILE;
    const int y  = threadIdx.x;       // 256 threads = 256 image rows

    const float* row = v + ((size_t)c * H_ + (size_t)y) * W_;

#pragma unroll
    for (int r = 0; r < ITILE; ++r) {
        float gi = g1[i0 + r];        // uniform across block -> scalar load
        int   xi[4]; float wx[4];
        cubic_prep(gi, W_, xi, wx);
        hx[r][y] = wx[0] * row[xi[0]] + wx[1] * row[xi[1]]
                 + wx[2] * row[xi[2]] + wx[3] * row[xi[3]];
    }
    __syncthreads();

    const int j0 = threadIdx.x * 4;   // thread owns 4 consecutive j's
    float4 res[ITILE];
#pragma unroll
    for (int k = 0; k < 4; ++k) {
        int   j  = j0 + k;
        float gj = g0[j];
        int   yi[4]; float wy[4];
        cubic_prep(gj, H_, yi, wy);
#pragma unroll
        for (int r = 0; r < ITILE; ++r) {
            float o = wy[0] * hx[r][yi[0]] + wy[1] * hx[r][yi[1]]
                    + wy[2] * hx[r][yi[2]] + wy[3] * hx[r][yi[3]];
            (&res[r].x)[k] = o;
        }
    }

#pragma unroll
    for (int r = 0; r < ITILE; ++r) {
        float* orow = out + ((size_t)c * L1_ + (size_t)(i0 + r)) * L0_;
        *reinterpret_cast<float4*>(orow + j0) = res[r];
    }
}

extern "C" void kernel_launch(void* const* d_in, const int* in_sizes, int n_in,
                              void* d_out, int out_size, void* d_ws, size_t ws_size,
                              hipStream_t stream) {
    const float* values = (const float*)d_in[0];  // (1, C, H, W) fp32
    const float* g0     = (const float*)d_in[1];  // (L0,) fp32 -> y axis
    const float* g1     = (const float*)d_in[2];  // (L1,) fp32 -> x axis
    float* out          = (float*)d_out;          // (1, C, L1, L0) fp32

    dim3 grid(L1_ / ITILE, C_);   // (256, 64) = 16384 blocks
    bicubic_kernel<<<grid, 256, 0, stream>>>(values, g0, g1, out);
}